// Round 1
// baseline (574.941 us; speedup 1.0000x reference)
//
#include <hip/hip_runtime.h>
#include <float.h>

#define N_ROWS 65536
#define DIM    256
#define KCODES 1024
#define BM     64      // rows per block
#define DC     32      // d-slice per LDS stage
#define VQ_BETA 0.25

// ---------------------------------------------------------------------------
// Kernel 0: transpose E [256][1024] -> Et [1024][256] (so both GEMM operands
// are d-major and stage with coalesced float4 loads).
__global__ void transpose_e(const float* __restrict__ E, float* __restrict__ Et) {
    __shared__ float t[32][33];
    const int kt = blockIdx.x * 32;       // 32 k-tiles
    const int dt = blockIdx.y * 32;       // 8  d-tiles
    const int lx = threadIdx.x & 31;
    const int ly = threadIdx.x >> 5;      // 0..7
#pragma unroll
    for (int i = 0; i < 4; ++i) {
        int d = dt + ly + i * 8;
        t[ly + i * 8][lx] = E[(size_t)d * KCODES + kt + lx];
    }
    __syncthreads();
#pragma unroll
    for (int i = 0; i < 4; ++i) {
        int k = kt + ly + i * 8;
        Et[(size_t)k * DIM + dt + lx] = t[lx][ly + i * 8];
    }
}

// ---------------------------------------------------------------------------
// Kernel 1: e_norm[k] = sum_d E[d][k]^2  (column reads are coalesced: fixed d,
// consecutive k across lanes).
__global__ void enorm_kernel(const float* __restrict__ E, float* __restrict__ enorm) {
    const int k = blockIdx.x * 256 + threadIdx.x;
    float s = 0.f;
#pragma unroll 4
    for (int d = 0; d < DIM; ++d) {
        float v = E[(size_t)d * KCODES + k];
        s = fmaf(v, v, s);
    }
    enorm[k] = s;
}

// ---------------------------------------------------------------------------
// Kernel 2: fused distance-GEMM + argmin + gather + quantized write + loss
// partial. Block: 256 threads, 64 rows. Per-thread 8 rows x 8 codes register
// tile; codes strided by 32 so E-tile LDS reads are only 4-way conflicted.
__global__ __launch_bounds__(256) void vq_main(
        const float* __restrict__ X, const float* __restrict__ Et,
        const float* __restrict__ enorm, float* __restrict__ outq,
        float* __restrict__ outidx, float* __restrict__ partials)
{
    __shared__ float Xs[64][36];       // 9.2 KB, padded (36 words: 16B aligned)
    __shared__ float Es[256][36];      // 36.9 KB
    __shared__ float enorm_s[KCODES];  // 4 KB
    __shared__ int   idx_s[64];
    __shared__ float red[256];

    const int tid = threadIdx.x;
    const int tr  = tid >> 5;          // 0..7  (row group)
    const int tc  = tid & 31;          // 0..31 (code lane)
    const int rowbase = blockIdx.x * BM;

    for (int i = tid; i < KCODES; i += 256) enorm_s[i] = enorm[i];

    float best[8], x2[8];
    int   bidx[8];
#pragma unroll
    for (int r = 0; r < 8; ++r) { best[r] = FLT_MAX; bidx[r] = 0; x2[r] = 0.f; }

    for (int nc = 0; nc < 4; ++nc) {           // 4 chunks of 256 codes
        float acc[8][8];
#pragma unroll
        for (int r = 0; r < 8; ++r)
#pragma unroll
            for (int c = 0; c < 8; ++c) acc[r][c] = 0.f;

        for (int dc = 0; dc < 8; ++dc) {       // 8 d-slices of 32
            __syncthreads();
            // stage X tile: 64 rows x 32 d (512 float4 items, 2/thread)
            {
                int it = tid;
#pragma unroll
                for (int s = 0; s < 2; ++s) {
                    int row = it >> 3, dg = it & 7;
                    float4 v = *reinterpret_cast<const float4*>(
                        X + (size_t)(rowbase + row) * DIM + dc * DC + dg * 4);
                    *reinterpret_cast<float4*>(&Xs[row][dg * 4]) = v;
                    it += 256;
                }
            }
            // stage E tile: 256 codes x 32 d (2048 float4 items, 8/thread)
            {
                int it = tid;
#pragma unroll
                for (int s = 0; s < 8; ++s) {
                    int k = it >> 3, dg = it & 7;
                    float4 v = *reinterpret_cast<const float4*>(
                        Et + (size_t)(nc * 256 + k) * DIM + dc * DC + dg * 4);
                    *reinterpret_cast<float4*>(&Es[k][dg * 4]) = v;
                    it += 256;
                }
            }
            __syncthreads();

#pragma unroll 2
            for (int dg = 0; dg < 8; ++dg) {
                float4 xv[8];
#pragma unroll
                for (int r = 0; r < 8; ++r)
                    xv[r] = *reinterpret_cast<const float4*>(&Xs[tr * 8 + r][dg * 4]);
                if (nc == 0) {
#pragma unroll
                    for (int r = 0; r < 8; ++r) {
                        x2[r] = fmaf(xv[r].x, xv[r].x, x2[r]);
                        x2[r] = fmaf(xv[r].y, xv[r].y, x2[r]);
                        x2[r] = fmaf(xv[r].z, xv[r].z, x2[r]);
                        x2[r] = fmaf(xv[r].w, xv[r].w, x2[r]);
                    }
                }
#pragma unroll
                for (int ci = 0; ci < 8; ++ci) {
                    float4 ev = *reinterpret_cast<const float4*>(&Es[ci * 32 + tc][dg * 4]);
#pragma unroll
                    for (int r = 0; r < 8; ++r) {
                        float a = acc[r][ci];
                        a = fmaf(xv[r].x, ev.x, a);
                        a = fmaf(xv[r].y, ev.y, a);
                        a = fmaf(xv[r].z, ev.z, a);
                        a = fmaf(xv[r].w, ev.w, a);
                        acc[r][ci] = a;
                    }
                }
            }
        }
        // argmin update — codes ascend with (nc, ci); strict < keeps first index
#pragma unroll
        for (int ci = 0; ci < 8; ++ci) {
            int code = nc * 256 + ci * 32 + tc;
            float e2 = enorm_s[code];
#pragma unroll
            for (int r = 0; r < 8; ++r) {
                float dist = (x2[r] - 2.0f * acc[r][ci]) + e2;
                if (dist < best[r]) { best[r] = dist; bidx[r] = code; }
            }
        }
    }

    // reduce across the 32 code-lanes (xor masks < 32 stay inside each half-wave)
#pragma unroll
    for (int m = 1; m < 32; m <<= 1) {
#pragma unroll
        for (int r = 0; r < 8; ++r) {
            float ob = __shfl_xor(best[r], m, 64);
            int   oi = __shfl_xor(bidx[r], m, 64);
            if (ob < best[r] || (ob == best[r] && oi < bidx[r])) {
                best[r] = ob; bidx[r] = oi;
            }
        }
    }
    if (tc == 0) {
#pragma unroll
        for (int r = 0; r < 8; ++r) {
            int row = tr * 8 + r;
            idx_s[row] = bidx[r];
            outidx[rowbase + row] = (float)bidx[r];   // indices as f32 values
        }
    }
    __syncthreads();

    // gather codebook row, write quantized (STE rounding: x + (q-x)), loss partial
    float lsum = 0.f;
    {
        const int row  = tid >> 2;
        const int part = tid & 3;
        const int code = idx_s[row];
        const size_t gbase = (size_t)(rowbase + row) * DIM;
#pragma unroll
        for (int j = 0; j < 16; ++j) {
            int d0 = j * 16 + part * 4;
            float4 q = *reinterpret_cast<const float4*>(Et + (size_t)code * DIM + d0);
            float4 x = *reinterpret_cast<const float4*>(X + gbase + d0);
            float4 o;
            o.x = x.x + (q.x - x.x);
            o.y = x.y + (q.y - x.y);
            o.z = x.z + (q.z - x.z);
            o.w = x.w + (q.w - x.w);
            *reinterpret_cast<float4*>(outq + gbase + d0) = o;
            float dx = q.x - x.x; lsum = fmaf(dx, dx, lsum);
            dx = q.y - x.y; lsum = fmaf(dx, dx, lsum);
            dx = q.z - x.z; lsum = fmaf(dx, dx, lsum);
            dx = q.w - x.w; lsum = fmaf(dx, dx, lsum);
        }
    }
    red[tid] = lsum;
    __syncthreads();
    for (int s = 128; s > 0; s >>= 1) {
        if (tid < s) red[tid] += red[tid + s];
        __syncthreads();
    }
    if (tid == 0) partials[blockIdx.x] = red[0];
}

// ---------------------------------------------------------------------------
// Kernel 3: deterministic final loss reduction (f64 accumulate).
__global__ void loss_final(const float* __restrict__ partials, float* __restrict__ out) {
    __shared__ double sd[256];
    const int tid = threadIdx.x;
    double s = 0.0;
    for (int i = tid; i < 1024; i += 256) s += (double)partials[i];
    sd[tid] = s;
    __syncthreads();
    for (int k = 128; k > 0; k >>= 1) {
        if (tid < k) sd[tid] += sd[tid + k];
        __syncthreads();
    }
    if (tid == 0) out[0] = (float)(VQ_BETA * sd[0] / (double)((size_t)N_ROWS * DIM));
}

// ---------------------------------------------------------------------------
extern "C" void kernel_launch(void* const* d_in, const int* in_sizes, int n_in,
                              void* d_out, int out_size, void* d_ws, size_t ws_size,
                              hipStream_t stream) {
    const float* X = (const float*)d_in[0];   // [65536][256]
    const float* E = (const float*)d_in[1];   // [256][1024]

    float* outq    = (float*)d_out;           // [16777216] quantized
    float* outloss = outq + (size_t)N_ROWS * DIM;   // [1] loss
    float* outidx  = outloss + 1;             // [65536] indices as float

    float* Et       = (float*)d_ws;           // [1024][256]  (1 MB)
    float* enormw   = Et + (size_t)KCODES * DIM;    // [1024]
    float* partials = enormw + KCODES;        // [1024]

    transpose_e <<<dim3(32, 8), 256, 0, stream>>>(E, Et);
    enorm_kernel<<<4,          256, 0, stream>>>(E, enormw);
    vq_main     <<<N_ROWS / BM, 256, 0, stream>>>(X, Et, enormw, outq, outidx, partials);
    loss_final  <<<1,          256, 0, stream>>>(partials, outloss);
}

// Round 5
// 358.215 us; speedup vs baseline: 1.6050x; 1.6050x over previous
//
#include <hip/hip_runtime.h>
#include <float.h>

typedef _Float16 half8 __attribute__((ext_vector_type(8)));
typedef float    f32x4 __attribute__((ext_vector_type(4)));

#define N_ROWS   65536
#define DIM      256
#define KCODES   1024
#define VQ_BETA  0.25
#define MARGIN   2.5f   // > 2 * hard bound (0.62) on fp16 distance error
#define HCAP     2048

// ---------------------------------------------------------------------------
// Kernel 0: transpose E [256][1024] -> Et [1024][256] fp32 (rescore + gather)
__global__ void transpose_e(const float* __restrict__ E, float* __restrict__ Et) {
    __shared__ float t[32][33];
    const int kt = blockIdx.x * 32;
    const int dt = blockIdx.y * 32;
    const int lx = threadIdx.x & 31;
    const int ly = threadIdx.x >> 5;
#pragma unroll
    for (int i = 0; i < 4; ++i) {
        int d = dt + ly + i * 8;
        t[ly + i * 8][lx] = E[(size_t)d * KCODES + kt + lx];
    }
    __syncthreads();
#pragma unroll
    for (int i = 0; i < 4; ++i) {
        int k = kt + ly + i * 8;
        Et[(size_t)k * DIM + dt + lx] = t[lx][ly + i * 8];
    }
}

// ---------------------------------------------------------------------------
// Kernel 1: e_norm[k] = sum_d E[d][k]^2 (fp32, sequential d order)
__global__ void enorm_kernel(const float* __restrict__ E, float* __restrict__ enorm) {
    const int k = blockIdx.x * 256 + threadIdx.x;
    float s = 0.f;
#pragma unroll 4
    for (int d = 0; d < DIM; ++d) {
        float v = E[(size_t)d * KCODES + k];
        s = fmaf(v, v, s);
    }
    enorm[k] = s;
}

// ---------------------------------------------------------------------------
// Kernel 2: pack Et into fp16 B-fragment slices.
__global__ void efrag_kernel(const float* __restrict__ Et, _Float16* __restrict__ Efrag) {
    const int cidx  = blockIdx.x * 256 + threadIdx.x;   // 0..32767
    const int slice = cidx >> 10;
    const int i16   = cidx & 1023;
    const int c = i16 >> 2, g = i16 & 3;
    const int code  = (slice >> 3) * 256 + c;
    const int kbase = (slice & 7) * 32 + g * 8;
    const float* src = Et + (size_t)code * DIM + kbase;
    half8 h;
#pragma unroll
    for (int j = 0; j < 8; ++j) h[j] = (_Float16)src[j];
    *reinterpret_cast<half8*>(Efrag + (size_t)cidx * 8) = h;
}

// ---------------------------------------------------------------------------
// Kernel 3: two-pass pruned argmin.
// Phase A: fp16 MFMA over all codes, per-row min of (e2 - 2*S~).
// Phase B: bitwise-identical MFMA re-run; codes with d~ < min + MARGIN -> list.
// Rescore: per-candidate SEQUENTIAL fp32 fma chain (bitwise round-1 = np-safe
// arithmetic); winner via two-phase atomicMin == np first-min semantics.
__global__ __launch_bounds__(256) void vq_mfma(
        const float* __restrict__ X, const _Float16* __restrict__ Efrag,
        const float* __restrict__ enorm, const float* __restrict__ Et,
        int* __restrict__ widx)
{
    __shared__ _Float16 Ah[64 * 256];     // 32 KB
    __shared__ _Float16 Bs[256 * 32];     // 16 KB (reused as dstore after phase B)
    __shared__ float    enorm_s[KCODES];  // 4 KB
    __shared__ float    x2s[64];
    __shared__ float    bminw[4][64];
    __shared__ float    cutoff_s[64];
    __shared__ unsigned minb[64], mini[64];
    __shared__ int      hits[HCAP];       // 8 KB
    __shared__ unsigned hitcnt;
    __shared__ int      ovf;

    const int tid = threadIdx.x;
    const int rowbase = blockIdx.x * 64;

    if (tid == 0) { hitcnt = 0; ovf = 0; }
    if (tid < 64) { minb[tid] = 0xFFFFFFFFu; mini[tid] = 0xFFFFFFFFu; }
    for (int i = tid; i < KCODES; i += 256) enorm_s[i] = enorm[i];

    // ---- stage A: fp32 -> fp16 swizzled LDS (+x2s for the ovf fallback) ----
    {
        const int row = tid >> 2;
        float x2p = 0.f;
#pragma unroll
        for (int i = 0; i < 8; ++i) {
            const int g = (tid & 3) + 4 * i;
            const float* src = X + (size_t)(rowbase + row) * DIM + g * 8;
            float4 a = *reinterpret_cast<const float4*>(src);
            float4 b = *reinterpret_cast<const float4*>(src + 4);
            x2p = fmaf(a.x, a.x, x2p); x2p = fmaf(a.y, a.y, x2p);
            x2p = fmaf(a.z, a.z, x2p); x2p = fmaf(a.w, a.w, x2p);
            x2p = fmaf(b.x, b.x, x2p); x2p = fmaf(b.y, b.y, x2p);
            x2p = fmaf(b.z, b.z, x2p); x2p = fmaf(b.w, b.w, x2p);
            half8 h;
            h[0] = (_Float16)a.x; h[1] = (_Float16)a.y;
            h[2] = (_Float16)a.z; h[3] = (_Float16)a.w;
            h[4] = (_Float16)b.x; h[5] = (_Float16)b.y;
            h[6] = (_Float16)b.z; h[7] = (_Float16)b.w;
            const int addr = (row * 512 + g * 16) ^ ((row & 7) << 4);
            *reinterpret_cast<half8*>(reinterpret_cast<char*>(Ah) + addr) = h;
        }
        x2p += __shfl_xor(x2p, 1, 64);
        x2p += __shfl_xor(x2p, 2, 64);
        if ((tid & 3) == 0) x2s[row] = x2p;
    }
    __syncthreads();

    const int w    = tid >> 6;
    const int lane = tid & 63;
    const int lhi  = lane >> 4, llo = lane & 15;
    const int aswz = (llo & 7) << 4;

    // =============================== PHASE A ===============================
    float minv[16];
#pragma unroll
    for (int sl = 0; sl < 16; ++sl) minv[sl] = FLT_MAX;

    for (int chunk = 0; chunk < 4; ++chunk) {
        f32x4 acc[4][4];
#pragma unroll
        for (int mt = 0; mt < 4; ++mt)
#pragma unroll
            for (int nt = 0; nt < 4; ++nt) acc[mt][nt] = (f32x4){0.f, 0.f, 0.f, 0.f};

        for (int ks = 0; ks < 8; ++ks) {
            __syncthreads();
            {
                const _Float16* src = Efrag + (size_t)(chunk * 8 + ks) * 8192;
#pragma unroll
                for (int s = 0; s < 4; ++s) {
                    const int i16 = tid + s * 256;
                    const int c = i16 >> 2, g = i16 & 3;
                    float4 v = *reinterpret_cast<const float4*>(src + (size_t)i16 * 8);
                    const int addr = (c * 64 + g * 16) ^ ((c & 7) << 4);
                    *reinterpret_cast<float4*>(reinterpret_cast<char*>(Bs) + addr) = v;
                }
            }
            __syncthreads();

            half8 af[4], bf[4];
#pragma unroll
            for (int mt = 0; mt < 4; ++mt) {
                const int addr = ((mt * 16 + llo) * 512 + (ks * 4 + lhi) * 16) ^ aswz;
                af[mt] = *reinterpret_cast<const half8*>(
                    reinterpret_cast<const char*>(Ah) + addr);
            }
#pragma unroll
            for (int nt = 0; nt < 4; ++nt) {
                const int c = w * 64 + nt * 16 + llo;
                const int addr = (c * 64 + lhi * 16) ^ ((c & 7) << 4);
                bf[nt] = *reinterpret_cast<const half8*>(
                    reinterpret_cast<const char*>(Bs) + addr);
            }
#pragma unroll
            for (int mt = 0; mt < 4; ++mt)
#pragma unroll
                for (int nt = 0; nt < 4; ++nt)
                    acc[mt][nt] = __builtin_amdgcn_mfma_f32_16x16x32_f16(
                        af[mt], bf[nt], acc[mt][nt], 0, 0, 0);
        }
#pragma unroll
        for (int nt = 0; nt < 4; ++nt) {
            const int code = chunk * 256 + w * 64 + nt * 16 + llo;
            const float e2 = enorm_s[code];
#pragma unroll
            for (int mt = 0; mt < 4; ++mt)
#pragma unroll
                for (int q = 0; q < 4; ++q) {
                    const float ds = fmaf(-2.0f, acc[mt][nt][q], e2);
                    const int sl = mt * 4 + q;
                    minv[sl] = fminf(minv[sl], ds);
                }
        }
    }
#pragma unroll
    for (int m = 1; m < 16; m <<= 1)
#pragma unroll
        for (int sl = 0; sl < 16; ++sl)
            minv[sl] = fminf(minv[sl], __shfl_xor(minv[sl], m, 64));
    if (llo == 0) {
#pragma unroll
        for (int mt = 0; mt < 4; ++mt)
#pragma unroll
            for (int q = 0; q < 4; ++q)
                bminw[w][mt * 16 + lhi * 4 + q] = minv[mt * 4 + q];
    }
    __syncthreads();
    if (tid < 64)
        cutoff_s[tid] = fminf(fminf(bminw[0][tid], bminw[1][tid]),
                              fminf(bminw[2][tid], bminw[3][tid])) + MARGIN;
    __syncthreads();

    // =============================== PHASE B ===============================
    float cut[16];
#pragma unroll
    for (int mt = 0; mt < 4; ++mt)
#pragma unroll
        for (int q = 0; q < 4; ++q)
            cut[mt * 4 + q] = cutoff_s[mt * 16 + lhi * 4 + q];

    for (int chunk = 0; chunk < 4; ++chunk) {
        f32x4 acc[4][4];
#pragma unroll
        for (int mt = 0; mt < 4; ++mt)
#pragma unroll
            for (int nt = 0; nt < 4; ++nt) acc[mt][nt] = (f32x4){0.f, 0.f, 0.f, 0.f};

        for (int ks = 0; ks < 8; ++ks) {
            __syncthreads();
            {
                const _Float16* src = Efrag + (size_t)(chunk * 8 + ks) * 8192;
#pragma unroll
                for (int s = 0; s < 4; ++s) {
                    const int i16 = tid + s * 256;
                    const int c = i16 >> 2, g = i16 & 3;
                    float4 v = *reinterpret_cast<const float4*>(src + (size_t)i16 * 8);
                    const int addr = (c * 64 + g * 16) ^ ((c & 7) << 4);
                    *reinterpret_cast<float4*>(reinterpret_cast<char*>(Bs) + addr) = v;
                }
            }
            __syncthreads();

            half8 af[4], bf[4];
#pragma unroll
            for (int mt = 0; mt < 4; ++mt) {
                const int addr = ((mt * 16 + llo) * 512 + (ks * 4 + lhi) * 16) ^ aswz;
                af[mt] = *reinterpret_cast<const half8*>(
                    reinterpret_cast<const char*>(Ah) + addr);
            }
#pragma unroll
            for (int nt = 0; nt < 4; ++nt) {
                const int c = w * 64 + nt * 16 + llo;
                const int addr = (c * 64 + lhi * 16) ^ ((c & 7) << 4);
                bf[nt] = *reinterpret_cast<const half8*>(
                    reinterpret_cast<const char*>(Bs) + addr);
            }
#pragma unroll
            for (int mt = 0; mt < 4; ++mt)
#pragma unroll
                for (int nt = 0; nt < 4; ++nt)
                    acc[mt][nt] = __builtin_amdgcn_mfma_f32_16x16x32_f16(
                        af[mt], bf[nt], acc[mt][nt], 0, 0, 0);
        }
#pragma unroll
        for (int nt = 0; nt < 4; ++nt) {
            const int code = chunk * 256 + w * 64 + nt * 16 + llo;
            const float e2 = enorm_s[code];
#pragma unroll
            for (int mt = 0; mt < 4; ++mt)
#pragma unroll
                for (int q = 0; q < 4; ++q) {
                    const float ds = fmaf(-2.0f, acc[mt][nt][q], e2);
                    const int sl = mt * 4 + q;
                    if (ds < cut[sl]) {                 // candidate
                        const unsigned p = atomicAdd(&hitcnt, 1u);
                        if (p < HCAP)
                            hits[p] = ((mt * 16 + lhi * 4 + q) << 10) | code;
                        else
                            ovf = 1;
                    }
                }
        }
    }
    __syncthreads();

    // ============================ EXACT RESCORE ============================
    // One thread per candidate; SEQUENTIAL d=0..255 fma chains for p and x2
    // (bitwise-identical to the round-1 arithmetic that measured absmax 0).
    float* dstore = reinterpret_cast<float*>(Bs);   // Bs is dead now
    const int nh = (int)(hitcnt < HCAP ? hitcnt : (unsigned)HCAP);

    if (!ovf) {
        for (int hi = tid; hi < nh; hi += 256) {
            const int pk = hits[hi];
            const int rl = pk >> 10, code = pk & 1023;
            const float* xr = X  + (size_t)(rowbase + rl) * DIM;
            const float* er = Et + (size_t)code * DIM;
            float p = 0.f, x2 = 0.f;
#pragma unroll
            for (int j = 0; j < 64; ++j) {          // ascending d, fixed order
                float4 xv = *reinterpret_cast<const float4*>(xr + j * 4);
                float4 ev = *reinterpret_cast<const float4*>(er + j * 4);
                x2 = fmaf(xv.x, xv.x, x2); x2 = fmaf(xv.y, xv.y, x2);
                x2 = fmaf(xv.z, xv.z, x2); x2 = fmaf(xv.w, xv.w, x2);
                p  = fmaf(xv.x, ev.x, p);  p  = fmaf(xv.y, ev.y, p);
                p  = fmaf(xv.z, ev.z, p);  p  = fmaf(xv.w, ev.w, p);
            }
            const float dd = (x2 - 2.0f * p) + enorm_s[code];
            dstore[hi] = dd;
            atomicMin(&minb[rl], __float_as_uint(dd));
        }
        __syncthreads();
        // lowest index among bit-equal minima == np first-min tie-break
        for (int hi = tid; hi < nh; hi += 256) {
            const int pk = hits[hi];
            const int rl = pk >> 10;
            if (__float_as_uint(dstore[hi]) == minb[rl])
                atomicMin(&mini[rl], (unsigned)(pk & 1023));
        }
    } else {
        // overflow fallback (statistically never): full exact scan, 4 thr/row,
        // sequential-d dot chains.
        const int rl = tid >> 2, part = tid & 3;
        const float* xr = X + (size_t)(rowbase + rl) * DIM;
        float bd = FLT_MAX; int bk = 0;
        for (int c = part; c < KCODES; c += 4) {
            const float* er = Et + (size_t)c * DIM;
            float p = 0.f;
#pragma unroll 4
            for (int d = 0; d < DIM; d += 4) {
                float4 xv = *reinterpret_cast<const float4*>(xr + d);
                float4 ev = *reinterpret_cast<const float4*>(er + d);
                p = fmaf(xv.x, ev.x, p); p = fmaf(xv.y, ev.y, p);
                p = fmaf(xv.z, ev.z, p); p = fmaf(xv.w, ev.w, p);
            }
            const float dd = (x2s[rl] - 2.0f * p) + enorm_s[c];
            if (dd < bd) { bd = dd; bk = c; }
        }
        atomicMin(&minb[rl], __float_as_uint(bd));
        __syncthreads();
        if (__float_as_uint(bd) == minb[rl])
            atomicMin(&mini[rl], (unsigned)bk);
    }
    __syncthreads();

    if (tid < 64) widx[rowbase + tid] = (int)mini[tid];
}

// ---------------------------------------------------------------------------
// Kernel 4: gather + STE write + indices-as-float + loss partials. HBM-bound.
__global__ __launch_bounds__(256) void quantize_ep(
        const float* __restrict__ X, const float* __restrict__ Et,
        const int* __restrict__ widx, float* __restrict__ outidx,
        float* __restrict__ outq, float* __restrict__ partials)
{
    __shared__ float red[256];
    const int tid  = threadIdx.x;
    const int rowl = tid >> 3;
    const int part = tid & 7;
    const int rowg = blockIdx.x * 32 + rowl;
    const int cw = widx[rowg];
    const float* xrow = X  + (size_t)rowg * DIM;
    const float* ew   = Et + (size_t)cw * DIM;
    if (part == 0) outidx[rowg] = (float)cw;

    float lsum = 0.f;
#pragma unroll
    for (int j = 0; j < 8; ++j) {
        const int d0 = j * 32 + part * 4;
        float4 q = *reinterpret_cast<const float4*>(ew + d0);
        float4 x = *reinterpret_cast<const float4*>(xrow + d0);
        float4 o;
        o.x = x.x + (q.x - x.x);
        o.y = x.y + (q.y - x.y);
        o.z = x.z + (q.z - x.z);
        o.w = x.w + (q.w - x.w);
        *reinterpret_cast<float4*>(outq + (size_t)rowg * DIM + d0) = o;
        float dx;
        dx = q.x - x.x; lsum = fmaf(dx, dx, lsum);
        dx = q.y - x.y; lsum = fmaf(dx, dx, lsum);
        dx = q.z - x.z; lsum = fmaf(dx, dx, lsum);
        dx = q.w - x.w; lsum = fmaf(dx, dx, lsum);
    }
    red[tid] = lsum;
    __syncthreads();
    for (int s = 128; s > 0; s >>= 1) {
        if (tid < s) red[tid] += red[tid + s];
        __syncthreads();
    }
    if (tid == 0) partials[blockIdx.x] = red[0];
}

// ---------------------------------------------------------------------------
__global__ void loss_final(const float* __restrict__ partials, float* __restrict__ out) {
    __shared__ double sd[256];
    const int tid = threadIdx.x;
    double s = 0.0;
    for (int i = tid; i < 2048; i += 256) s += (double)partials[i];
    sd[tid] = s;
    __syncthreads();
    for (int k = 128; k > 0; k >>= 1) {
        if (tid < k) sd[tid] += sd[tid + k];
        __syncthreads();
    }
    if (tid == 0) out[0] = (float)(VQ_BETA * sd[0] / (double)((size_t)N_ROWS * DIM));
}

// ---------------------------------------------------------------------------
extern "C" void kernel_launch(void* const* d_in, const int* in_sizes, int n_in,
                              void* d_out, int out_size, void* d_ws, size_t ws_size,
                              hipStream_t stream) {
    const float* X = (const float*)d_in[0];   // [65536][256]
    const float* E = (const float*)d_in[1];   // [256][1024]

    float* outq    = (float*)d_out;                       // [16777216]
    float* outloss = outq + (size_t)N_ROWS * DIM;         // [1]
    float* outidx  = outloss + 1;                         // [65536] (float-coded)

    float*    Et       = (float*)d_ws;                    // 1 MB
    _Float16* Efrag    = (_Float16*)(Et + 262144);        // 512 KB
    float*    enormw   = (float*)(Efrag + 262144);        // 4 KB
    float*    partials = enormw + KCODES;                 // 8 KB (2048)
    int*      widx     = (int*)(partials + 2048);         // 256 KB

    transpose_e <<<dim3(32, 8), 256, 0, stream>>>(E, Et);
    enorm_kernel<<<4,           256, 0, stream>>>(E, enormw);
    efrag_kernel<<<128,         256, 0, stream>>>(Et, Efrag);
    vq_mfma     <<<N_ROWS / 64, 256, 0, stream>>>(X, Efrag, enormw, Et, widx);
    quantize_ep <<<N_ROWS / 32, 256, 0, stream>>>(X, Et, widx, outidx, outq, partials);
    loss_final  <<<1,           256, 0, stream>>>(partials, outloss);
}

// Round 6
// 190.350 us; speedup vs baseline: 3.0204x; 1.8819x over previous
//
#include <hip/hip_runtime.h>
#include <float.h>

typedef _Float16 half8 __attribute__((ext_vector_type(8)));
typedef float    f32x4 __attribute__((ext_vector_type(4)));

#define N_ROWS   65536
#define DIM      256
#define KCODES   1024
#define VQ_BETA  0.25
#define MARGIN   2.5f   // > 2 * hard bound (0.58) on fp16 distance error
#define HCAP     1024

// ---------------------------------------------------------------------------
// Kernel 0: transpose E [256][1024] -> Et [1024][256] fp32 (rescore + gather)
__global__ void transpose_e(const float* __restrict__ E, float* __restrict__ Et) {
    __shared__ float t[32][33];
    const int kt = blockIdx.x * 32;
    const int dt = blockIdx.y * 32;
    const int lx = threadIdx.x & 31;
    const int ly = threadIdx.x >> 5;
#pragma unroll
    for (int i = 0; i < 4; ++i) {
        int d = dt + ly + i * 8;
        t[ly + i * 8][lx] = E[(size_t)d * KCODES + kt + lx];
    }
    __syncthreads();
#pragma unroll
    for (int i = 0; i < 4; ++i) {
        int k = kt + ly + i * 8;
        Et[(size_t)k * DIM + dt + lx] = t[lx][ly + i * 8];
    }
}

// ---------------------------------------------------------------------------
// Kernel 1: e_norm[k] = sum_d E[d][k]^2 (fp32, sequential d order)
__global__ void enorm_kernel(const float* __restrict__ E, float* __restrict__ enorm) {
    const int k = blockIdx.x * 256 + threadIdx.x;
    float s = 0.f;
#pragma unroll 4
    for (int d = 0; d < DIM; ++d) {
        float v = E[(size_t)d * KCODES + k];
        s = fmaf(v, v, s);
    }
    enorm[k] = s;
}

// ---------------------------------------------------------------------------
// Kernel 2: pack Et into fp16 B fragments, wave-coalesced layout:
// Efb[slice][w][nt][llo][lhi][j]  (slice=chunk*8+ks), so a (ks,nt) fragment
// load is one contiguous 1KB segment per wave.
__global__ void efrag_kernel(const float* __restrict__ Et, _Float16* __restrict__ Efb) {
    const int fid = blockIdx.x * 256 + threadIdx.x;   // 0..32767
    const int lhi   = fid & 3;
    const int llo   = (fid >> 2) & 15;
    const int nt    = (fid >> 6) & 3;
    const int w     = (fid >> 8) & 3;
    const int slice = fid >> 10;                      // 0..31
    const int chunk = slice >> 3, ks = slice & 7;
    const int code  = chunk * 256 + w * 64 + nt * 16 + llo;
    const float* src = Et + (size_t)code * DIM + ks * 32 + lhi * 8;
    half8 h;
#pragma unroll
    for (int j = 0; j < 8; ++j) h[j] = (_Float16)src[j];
    *reinterpret_cast<half8*>(Efb + (size_t)fid * 8) = h;
}

// ---------------------------------------------------------------------------
__device__ __forceinline__ void load_bf(const _Float16* __restrict__ eb,
                                        half8 (&bf)[4]) {
    bf[0] = *reinterpret_cast<const half8*>(eb);
    bf[1] = *reinterpret_cast<const half8*>(eb + 512);
    bf[2] = *reinterpret_cast<const half8*>(eb + 1024);
    bf[3] = *reinterpret_cast<const half8*>(eb + 1536);
}
__device__ __forceinline__ void load_af(const char* AhB, int ks, int llo, int lhi,
                                        int aswz, half8 (&af)[4]) {
#pragma unroll
    for (int mt = 0; mt < 4; ++mt) {
        const int addr = ((mt * 16 + llo) * 512 + (ks * 4 + lhi) * 16) ^ aswz;
        af[mt] = *reinterpret_cast<const half8*>(AhB + addr);
    }
}
__device__ __forceinline__ void mfma16(const half8 (&af)[4], const half8 (&bf)[4],
                                       f32x4 (&acc)[4][4]) {
#pragma unroll
    for (int mt = 0; mt < 4; ++mt)
#pragma unroll
        for (int nt = 0; nt < 4; ++nt)
            acc[mt][nt] = __builtin_amdgcn_mfma_f32_16x16x32_f16(
                af[mt], bf[nt], acc[mt][nt], 0, 0, 0);
}
// One 64-row x 64-code x K=256 accumulation; B direct from global (L2),
// A from swizzled LDS; bf manually double-buffered; NO barriers.
__device__ __forceinline__ void mfma_chunk(
        const _Float16* __restrict__ ebase, const char* AhB,
        int llo, int lhi, int aswz, f32x4 (&acc)[4][4]) {
    half8 bfa[4], bfb[4], af[4];
    load_bf(ebase, bfa);
#pragma unroll
    for (int ks2 = 0; ks2 < 4; ++ks2) {
        const int ksA = ks2 * 2, ksB = ks2 * 2 + 1;
        load_bf(ebase + (size_t)ksB * 8192, bfb);
        load_af(AhB, ksA, llo, lhi, aswz, af);
        mfma16(af, bfa, acc);
        if (ksB < 7) load_bf(ebase + (size_t)(ksB + 1) * 8192, bfa);
        load_af(AhB, ksB, llo, lhi, aswz, af);
        mfma16(af, bfb, acc);
    }
}

// ---------------------------------------------------------------------------
// Kernel 3: two-pass pruned argmin (barrier-free K-loop).
// Phase A: per-row min of ds = e2 - 2*S~ over all codes (fp16 MFMA).
// Phase B: bitwise-identical re-run; ds < min+MARGIN -> candidate list.
// Rescore: sequential fp32 fma chain per candidate (np-identical arithmetic);
// winner via two-phase atomicMin == np first-min tie-break.
__global__ __launch_bounds__(256, 2) void vq_mfma(
        const float* __restrict__ X, const _Float16* __restrict__ Efb,
        const float* __restrict__ enorm, const float* __restrict__ Et,
        int* __restrict__ widx)
{
    __shared__ _Float16 Ah[64 * 256];     // 32 KB, swizzled
    __shared__ float    x2s[64];
    __shared__ float    bminw[4][64];
    __shared__ float    cutoff_s[64];
    __shared__ unsigned minb[64], mini[64];
    __shared__ int      hits[HCAP];       // 4 KB
    __shared__ float    dstore[HCAP];     // 4 KB
    __shared__ unsigned hitcnt;
    __shared__ int      ovf;

    const int tid = threadIdx.x;
    const int rowbase = blockIdx.x * 64;

    if (tid == 0) { hitcnt = 0; ovf = 0; }
    if (tid < 64) { minb[tid] = 0xFFFFFFFFu; mini[tid] = 0xFFFFFFFFu; }

    // ---- stage A tile: fp32 -> fp16 swizzled LDS (+ x2s for ovf fallback) ----
    {
        const int row = tid >> 2;
        float x2p = 0.f;
#pragma unroll
        for (int i = 0; i < 8; ++i) {
            const int g = (tid & 3) + 4 * i;
            const float* src = X + (size_t)(rowbase + row) * DIM + g * 8;
            float4 a = *reinterpret_cast<const float4*>(src);
            float4 b = *reinterpret_cast<const float4*>(src + 4);
            x2p = fmaf(a.x, a.x, x2p); x2p = fmaf(a.y, a.y, x2p);
            x2p = fmaf(a.z, a.z, x2p); x2p = fmaf(a.w, a.w, x2p);
            x2p = fmaf(b.x, b.x, x2p); x2p = fmaf(b.y, b.y, x2p);
            x2p = fmaf(b.z, b.z, x2p); x2p = fmaf(b.w, b.w, x2p);
            half8 h;
            h[0] = (_Float16)a.x; h[1] = (_Float16)a.y;
            h[2] = (_Float16)a.z; h[3] = (_Float16)a.w;
            h[4] = (_Float16)b.x; h[5] = (_Float16)b.y;
            h[6] = (_Float16)b.z; h[7] = (_Float16)b.w;
            const int addr = (row * 512 + g * 16) ^ ((row & 7) << 4);
            *reinterpret_cast<half8*>(reinterpret_cast<char*>(Ah) + addr) = h;
        }
        x2p += __shfl_xor(x2p, 1, 64);
        x2p += __shfl_xor(x2p, 2, 64);
        if ((tid & 3) == 0) x2s[row] = x2p;
    }
    __syncthreads();

    const int w    = tid >> 6;
    const int lane = tid & 63;
    const int lhi  = lane >> 4, llo = lane & 15;
    const int aswz = (llo & 7) << 4;
    const int lane_off8 = (llo * 4 + lhi) * 8;
    const char* AhB = reinterpret_cast<const char*>(Ah);

    // =============================== PHASE A ===============================
    float minv[16];
#pragma unroll
    for (int sl = 0; sl < 16; ++sl) minv[sl] = FLT_MAX;

    for (int chunk = 0; chunk < 4; ++chunk) {
        f32x4 acc[4][4];
#pragma unroll
        for (int mt = 0; mt < 4; ++mt)
#pragma unroll
            for (int nt = 0; nt < 4; ++nt) acc[mt][nt] = (f32x4){0.f, 0.f, 0.f, 0.f};

        const _Float16* ebase = Efb + (size_t)chunk * 65536 + w * 2048 + lane_off8;
        mfma_chunk(ebase, AhB, llo, lhi, aswz, acc);

#pragma unroll
        for (int nt = 0; nt < 4; ++nt) {
            const float e2 = enorm[chunk * 256 + w * 64 + nt * 16 + llo];
#pragma unroll
            for (int mt = 0; mt < 4; ++mt)
#pragma unroll
                for (int q = 0; q < 4; ++q)
                    minv[mt * 4 + q] = fminf(minv[mt * 4 + q],
                                             fmaf(-2.0f, acc[mt][nt][q], e2));
        }
    }
#pragma unroll
    for (int m = 1; m < 16; m <<= 1)
#pragma unroll
        for (int sl = 0; sl < 16; ++sl)
            minv[sl] = fminf(minv[sl], __shfl_xor(minv[sl], m, 64));
    if (llo == 0) {
#pragma unroll
        for (int mt = 0; mt < 4; ++mt)
#pragma unroll
            for (int q = 0; q < 4; ++q)
                bminw[w][mt * 16 + lhi * 4 + q] = minv[mt * 4 + q];
    }
    __syncthreads();
    if (tid < 64)
        cutoff_s[tid] = fminf(fminf(bminw[0][tid], bminw[1][tid]),
                              fminf(bminw[2][tid], bminw[3][tid])) + MARGIN;
    __syncthreads();

    // =============================== PHASE B ===============================
    float cut[16];
#pragma unroll
    for (int mt = 0; mt < 4; ++mt)
#pragma unroll
        for (int q = 0; q < 4; ++q)
            cut[mt * 4 + q] = cutoff_s[mt * 16 + lhi * 4 + q];

    for (int chunk = 0; chunk < 4; ++chunk) {
        f32x4 acc[4][4];
#pragma unroll
        for (int mt = 0; mt < 4; ++mt)
#pragma unroll
            for (int nt = 0; nt < 4; ++nt) acc[mt][nt] = (f32x4){0.f, 0.f, 0.f, 0.f};

        const _Float16* ebase = Efb + (size_t)chunk * 65536 + w * 2048 + lane_off8;
        mfma_chunk(ebase, AhB, llo, lhi, aswz, acc);

#pragma unroll
        for (int nt = 0; nt < 4; ++nt) {
            const int code = chunk * 256 + w * 64 + nt * 16 + llo;
            const float e2 = enorm[code];
#pragma unroll
            for (int mt = 0; mt < 4; ++mt)
#pragma unroll
                for (int q = 0; q < 4; ++q) {
                    const float ds = fmaf(-2.0f, acc[mt][nt][q], e2);
                    if (ds < cut[mt * 4 + q]) {
                        const unsigned p = atomicAdd(&hitcnt, 1u);
                        if (p < HCAP)
                            hits[p] = ((mt * 16 + lhi * 4 + q) << 10) | code;
                        else
                            ovf = 1;
                    }
                }
        }
    }
    __syncthreads();

    // ============================ EXACT RESCORE ============================
    const int nh = (int)(hitcnt < HCAP ? hitcnt : (unsigned)HCAP);

    if (!ovf) {
        for (int hi = tid; hi < nh; hi += 256) {
            const int pk = hits[hi];
            const int rl = pk >> 10, code = pk & 1023;
            const float* xr = X  + (size_t)(rowbase + rl) * DIM;
            const float* er = Et + (size_t)code * DIM;
            float p = 0.f, x2 = 0.f;
#pragma unroll
            for (int j = 0; j < 64; ++j) {          // ascending d, fixed order
                float4 xv = *reinterpret_cast<const float4*>(xr + j * 4);
                float4 ev = *reinterpret_cast<const float4*>(er + j * 4);
                x2 = fmaf(xv.x, xv.x, x2); x2 = fmaf(xv.y, xv.y, x2);
                x2 = fmaf(xv.z, xv.z, x2); x2 = fmaf(xv.w, xv.w, x2);
                p  = fmaf(xv.x, ev.x, p);  p  = fmaf(xv.y, ev.y, p);
                p  = fmaf(xv.z, ev.z, p);  p  = fmaf(xv.w, ev.w, p);
            }
            const float dd = (x2 - 2.0f * p) + enorm[code];
            dstore[hi] = dd;
            atomicMin(&minb[rl], __float_as_uint(dd));
        }
        __syncthreads();
        for (int hi = tid; hi < nh; hi += 256) {
            const int pk = hits[hi];
            const int rl = pk >> 10;
            if (__float_as_uint(dstore[hi]) == minb[rl])
                atomicMin(&mini[rl], (unsigned)(pk & 1023));
        }
    } else {
        // overflow fallback (statistically never): full exact scan, 4 thr/row
        const int rl = tid >> 2, part = tid & 3;
        const float* xr = X + (size_t)(rowbase + rl) * DIM;
        float bd = FLT_MAX; int bk = 0;
        for (int c = part; c < KCODES; c += 4) {
            const float* er = Et + (size_t)c * DIM;
            float p = 0.f;
#pragma unroll 4
            for (int d = 0; d < DIM; d += 4) {
                float4 xv = *reinterpret_cast<const float4*>(xr + d);
                float4 ev = *reinterpret_cast<const float4*>(er + d);
                p = fmaf(xv.x, ev.x, p); p = fmaf(xv.y, ev.y, p);
                p = fmaf(xv.z, ev.z, p); p = fmaf(xv.w, ev.w, p);
            }
            const float dd = (x2s[rl] - 2.0f * p) + enorm[c];
            if (dd < bd) { bd = dd; bk = c; }
        }
        atomicMin(&minb[rl], __float_as_uint(bd));
        __syncthreads();
        if (__float_as_uint(bd) == minb[rl])
            atomicMin(&mini[rl], (unsigned)bk);
    }
    __syncthreads();

    if (tid < 64) widx[rowbase + tid] = (int)mini[tid];
}

// ---------------------------------------------------------------------------
// Kernel 4: gather + STE write + indices-as-float + loss partials. HBM-bound.
__global__ __launch_bounds__(256) void quantize_ep(
        const float* __restrict__ X, const float* __restrict__ Et,
        const int* __restrict__ widx, float* __restrict__ outidx,
        float* __restrict__ outq, float* __restrict__ partials)
{
    __shared__ float red[256];
    const int tid  = threadIdx.x;
    const int rowl = tid >> 3;
    const int part = tid & 7;
    const int rowg = blockIdx.x * 32 + rowl;
    const int cw = widx[rowg];
    const float* xrow = X  + (size_t)rowg * DIM;
    const float* ew   = Et + (size_t)cw * DIM;
    if (part == 0) outidx[rowg] = (float)cw;

    float lsum = 0.f;
#pragma unroll
    for (int j = 0; j < 8; ++j) {
        const int d0 = j * 32 + part * 4;
        float4 q = *reinterpret_cast<const float4*>(ew + d0);
        float4 x = *reinterpret_cast<const float4*>(xrow + d0);
        float4 o;
        o.x = x.x + (q.x - x.x);
        o.y = x.y + (q.y - x.y);
        o.z = x.z + (q.z - x.z);
        o.w = x.w + (q.w - x.w);
        *reinterpret_cast<float4*>(outq + (size_t)rowg * DIM + d0) = o;
        float dx;
        dx = q.x - x.x; lsum = fmaf(dx, dx, lsum);
        dx = q.y - x.y; lsum = fmaf(dx, dx, lsum);
        dx = q.z - x.z; lsum = fmaf(dx, dx, lsum);
        dx = q.w - x.w; lsum = fmaf(dx, dx, lsum);
    }
    red[tid] = lsum;
    __syncthreads();
    for (int s = 128; s > 0; s >>= 1) {
        if (tid < s) red[tid] += red[tid + s];
        __syncthreads();
    }
    if (tid == 0) partials[blockIdx.x] = red[0];
}

// ---------------------------------------------------------------------------
__global__ void loss_final(const float* __restrict__ partials, float* __restrict__ out) {
    __shared__ double sd[256];
    const int tid = threadIdx.x;
    double s = 0.0;
    for (int i = tid; i < 2048; i += 256) s += (double)partials[i];
    sd[tid] = s;
    __syncthreads();
    for (int k = 128; k > 0; k >>= 1) {
        if (tid < k) sd[tid] += sd[tid + k];
        __syncthreads();
    }
    if (tid == 0) out[0] = (float)(VQ_BETA * sd[0] / (double)((size_t)N_ROWS * DIM));
}

// ---------------------------------------------------------------------------
extern "C" void kernel_launch(void* const* d_in, const int* in_sizes, int n_in,
                              void* d_out, int out_size, void* d_ws, size_t ws_size,
                              hipStream_t stream) {
    const float* X = (const float*)d_in[0];   // [65536][256]
    const float* E = (const float*)d_in[1];   // [256][1024]

    float* outq    = (float*)d_out;                       // [16777216]
    float* outloss = outq + (size_t)N_ROWS * DIM;         // [1]
    float* outidx  = outloss + 1;                         // [65536] (float-coded)

    float*    Et       = (float*)d_ws;                    // 1 MB
    _Float16* Efb      = (_Float16*)(Et + 262144);        // 512 KB
    float*    enormw   = (float*)(Efb + 262144);          // 4 KB
    float*    partials = enormw + KCODES;                 // 8 KB (2048)
    int*      widx     = (int*)(partials + 2048);         // 256 KB

    transpose_e <<<dim3(32, 8), 256, 0, stream>>>(E, Et);
    enorm_kernel<<<4,           256, 0, stream>>>(E, enormw);
    efrag_kernel<<<128,         256, 0, stream>>>(Et, Efb);
    vq_mfma     <<<N_ROWS / 64, 256, 0, stream>>>(X, Efb, enormw, Et, widx);
    quantize_ep <<<N_ROWS / 32, 256, 0, stream>>>(X, Et, widx, outidx, outq, partials);
    loss_final  <<<1,           256, 0, stream>>>(partials, outloss);
}